// Round 5
// baseline (891.629 us; speedup 1.0000x reference)
//
#include <hip/hip_runtime.h>
#include <hip/hip_bf16.h>
#include <cstdint>

typedef short  bf16x8 __attribute__((ext_vector_type(8)));
typedef float  f32x4  __attribute__((ext_vector_type(4)));
typedef unsigned short u16x8 __attribute__((ext_vector_type(8)));

#define GLDS(gp, lp) __builtin_amdgcn_global_load_lds( \
    (const __attribute__((address_space(1))) void*)(gp), \
    (__attribute__((address_space(3))) void*)(lp), 16, 0, 0)

static constexpr int   MROWS = 16384;   // B*N = 16*1024
static constexpr int   N3    = 3072;    // 3*C
static constexpr int   NT    = 48;      // K-tiles of 64 (logical K = 3072)
static constexpr float SCALE = 0.125f;  // 8/64

__device__ __forceinline__ unsigned short f2bf(float f) {
  union { float f; unsigned u; } c; c.f = f;
  return (unsigned short)((c.u + 0x7fffu + ((c.u >> 16) & 1u)) >> 16);
}
__device__ __forceinline__ float bf2f(unsigned short h) {
  union { unsigned u; float f; } c; c.u = ((unsigned)h) << 16;
  return c.f;
}
// swap the two 5-bit (h,w) fields within each batch's 1024 rows (involution)
__device__ __forceinline__ int permrow(int m) {
  return (m & ~1023) | ((m & 31) << 5) | ((m >> 5) & 31);
}

// ---- split fp32 activations: row layout [hi(1024) | lo(1024)] bf16 ----
__global__ __launch_bounds__(256) void split_x(const float* __restrict__ src,
                                               unsigned short* __restrict__ dst) {
  int idx = blockIdx.x * 256 + threadIdx.x;
  int m = idx >> 7, k8 = (idx & 127) << 3;
  const float* s = src + (size_t)m * 1024 + k8;
  float4 v0 = *(const float4*)s;
  float4 v1 = *(const float4*)(s + 4);
  float vals[8] = {v0.x, v0.y, v0.z, v0.w, v1.x, v1.y, v1.z, v1.w};
  u16x8 hi, lo;
#pragma unroll
  for (int i = 0; i < 8; ++i) {
    unsigned short h = f2bf(vals[i]);
    hi[i] = h;
    lo[i] = f2bf(vals[i] - bf2f(h));
  }
  unsigned short* d = dst + (size_t)m * 2048 + k8;
  *(u16x8*)(d)        = hi;
  *(u16x8*)(d + 1024) = lo;
}

// ---- split fp32 weights into tripled [hi | lo | hi] bf16 ----
__global__ __launch_bounds__(256) void split_w(const float* __restrict__ src,
                                               unsigned short* __restrict__ dst) {
  int idx = blockIdx.x * 256 + threadIdx.x;
  int n = idx >> 7, k8 = (idx & 127) << 3;
  const float* s = src + (size_t)n * 1024 + k8;
  float4 v0 = *(const float4*)s;
  float4 v1 = *(const float4*)(s + 4);
  float vals[8] = {v0.x, v0.y, v0.z, v0.w, v1.x, v1.y, v1.z, v1.w};
  u16x8 hi, lo;
#pragma unroll
  for (int i = 0; i < 8; ++i) {
    unsigned short h = f2bf(vals[i]);
    hi[i] = h;
    lo[i] = f2bf(vals[i] - bf2f(h));
  }
  unsigned short* d = dst + (size_t)n * N3 + k8;
  *(u16x8*)(d)        = hi;
  *(u16x8*)(d + 1024) = lo;
  *(u16x8*)(d + 2048) = hi;
}

// ================= 256x256 8-wave GEMM, 4-phase/K-tile, deep pipeline ======
// C[m][n] = sum over logical K=3072: seg0 Ahi*Bhi, seg1 Ahi*Blo, seg2 Alo*Bhi
// A row layout [hi|lo] stride 2048 (kAof(s) = 64s - (s>=16 ? 1024:0)); B tripled.
// LDS: 2 bufs x (A 32KB + B 32KB), st_16x32 XOR swizzle via pre-swizzled source.
// Deep staging: at tile t, each phase restages a just-freed region for tile t+2
// (Bkk1(t+1)@ph1, Akk0(t+2)@ph2, Bkk0(t+2)@ph3, Akk1(t+2)@ph4). Gates vmcnt(10)
// keep 5 stage-units (10 loads/wave) in flight -> issue-to-read >= 5 phases.
__global__ __launch_bounds__(512, 2) void gemm256(const unsigned short* __restrict__ A,
                                                  const unsigned short* __restrict__ Bm,
                                                  unsigned short* __restrict__ Cq) {
  __shared__ unsigned char smem[131072];
  const int tid = threadIdx.x;
  const int w = tid >> 6, l = tid & 63;
  const int wr = w >> 2, wc = w & 3;          // 2 x 4 wave grid

  // XCD-chunked bijective mapping: each XCD (bid&7) owns 96 contiguous
  // (n-major, m-minor) tiles -> B panel L2-resident, A panels LLC-shared.
  const int bid = blockIdx.x;
  const int g = (bid & 7) * 96 + (bid >> 3);
  const int m0 = (g & 63) << 8;
  const int n0 = (g >> 6) << 8;

  // staging: wave w owns rows w*32..w*32+31 of each unit; pre-swizzled k source
  const int ske = ((l & 3) * 8) ^ ((l >= 32) ? 16 : 0);
  const unsigned short* gA0 = A  + (size_t)(m0 + w * 32 + (l >> 2)) * 2048 + ske;
  const unsigned short* gA1 = gA0 + 16 * 2048;
  const unsigned short* gB0 = Bm + (size_t)(n0 + w * 32 + (l >> 2)) * 3072 + ske;
  const unsigned short* gB1 = gB0 + (size_t)16 * 3072;

  // swizzled ds_read lane offset (16B frag at row lr, k-group l>>4)
  const int lr = l & 15;
  const int laneoff = ((lr * 64) + ((l >> 4) * 16)) ^ ((lr & 8) << 2);

#define STAGE_A(pb, kk, kof) do { \
    GLDS(gA0 + (kof) + (kk) * 32, smem + (pb) * 65536 + (4 * w + (kk)) * 1024); \
    GLDS(gA1 + (kof) + (kk) * 32, smem + (pb) * 65536 + (4 * w + 2 + (kk)) * 1024); } while (0)
#define STAGE_B(pb, kk, kof) do { \
    GLDS(gB0 + (kof) + (kk) * 32, smem + (pb) * 65536 + 32768 + (4 * w + (kk)) * 1024); \
    GLDS(gB1 + (kof) + (kk) * 32, smem + (pb) * 65536 + 32768 + (4 * w + 2 + (kk)) * 1024); } while (0)
#define MFMA(af, bf, c) __builtin_amdgcn_mfma_f32_16x16x32_bf16(af, bf, c, 0, 0, 0)

  f32x4 acc[8][4] = {};

  // ---- prologue: 7 units in issue order Ak0(0),Bk0(0),Ak1(0),Bk1(0),
  //                Ak0(1),Bk0(1),Ak1(1); gate ensures first 2 landed ----
  STAGE_A(0, 0, 0); STAGE_B(0, 0, 0); STAGE_A(0, 1, 0); STAGE_B(0, 1, 0);
  STAGE_A(1, 0, 64); STAGE_B(1, 0, 64); STAGE_A(1, 1, 64);
  asm volatile("s_waitcnt vmcnt(10)" ::: "memory");
  __builtin_amdgcn_s_barrier();

  for (int t = 0; t < NT; ++t) {
    const int p = t & 1, q = p ^ 1;
    const unsigned char* rb = smem + p * 65536;
    const int kB1 = (t + 1) * 64;
    const int kB2 = (t + 2) * 64;
    const int kA2 = kB2 - ((t + 2) >= 16 ? 1024 : 0);
    bf16x8 a[8], b0, b1, b2, b3;

    // ---------- phase 1: stage Bkk1(t+1)->buf q; read A-kk0, B0/1-kk0 ----------
    if (t < NT - 1) STAGE_B(q, 1, kB1);
#pragma unroll
    for (int mi = 0; mi < 8; ++mi)
      a[mi] = *(const bf16x8*)(rb + (wr * 8 + mi) * 2048 + laneoff);
    b0 = *(const bf16x8*)(rb + 32768 + (wc * 4 + 0) * 2048 + laneoff);
    b1 = *(const bf16x8*)(rb + 32768 + (wc * 4 + 1) * 2048 + laneoff);
    __builtin_amdgcn_s_barrier();
    asm volatile("s_waitcnt lgkmcnt(0)" ::: "memory");
    __builtin_amdgcn_sched_barrier(0);
    __builtin_amdgcn_s_setprio(1);
#pragma unroll
    for (int mi = 0; mi < 8; ++mi) {
      acc[mi][0] = MFMA(a[mi], b0, acc[mi][0]);
      acc[mi][1] = MFMA(a[mi], b1, acc[mi][1]);
    }
    __builtin_amdgcn_s_setprio(0);
    __builtin_amdgcn_s_barrier();

    // ---------- phase 2: stage Akk0(t+2)->buf p (freed by ph1); read B2/3-kk0 --
    if (t < NT - 2) STAGE_A(p, 0, kA2);
    b2 = *(const bf16x8*)(rb + 32768 + (wc * 4 + 2) * 2048 + laneoff);
    b3 = *(const bf16x8*)(rb + 32768 + (wc * 4 + 3) * 2048 + laneoff);
    __builtin_amdgcn_s_barrier();
    asm volatile("s_waitcnt lgkmcnt(0)" ::: "memory");
    __builtin_amdgcn_sched_barrier(0);
    __builtin_amdgcn_s_setprio(1);
#pragma unroll
    for (int mi = 0; mi < 8; ++mi) {
      acc[mi][2] = MFMA(a[mi], b2, acc[mi][2]);
      acc[mi][3] = MFMA(a[mi], b3, acc[mi][3]);
    }
    __builtin_amdgcn_s_setprio(0);
    // gate 1: Akk1(t), Bkk1(t) must land (5 units issued after them)
    if (t < NT - 2)       { asm volatile("s_waitcnt vmcnt(10)" ::: "memory"); }
    else if (t == NT - 2) { asm volatile("s_waitcnt vmcnt(8)"  ::: "memory"); }
    else                  { asm volatile("s_waitcnt vmcnt(0)"  ::: "memory"); }
    __builtin_amdgcn_s_barrier();

    // ---------- phase 3: stage Bkk0(t+2)->buf p (freed by ph2); read kk1 -------
    if (t < NT - 2) STAGE_B(p, 0, kB2);
#pragma unroll
    for (int mi = 0; mi < 8; ++mi)
      a[mi] = *(const bf16x8*)(rb + (wr * 8 + mi) * 2048 + 1024 + laneoff);
    b0 = *(const bf16x8*)(rb + 32768 + (wc * 4 + 0) * 2048 + 1024 + laneoff);
    b1 = *(const bf16x8*)(rb + 32768 + (wc * 4 + 1) * 2048 + 1024 + laneoff);
    __builtin_amdgcn_s_barrier();
    asm volatile("s_waitcnt lgkmcnt(0)" ::: "memory");
    __builtin_amdgcn_sched_barrier(0);
    __builtin_amdgcn_s_setprio(1);
#pragma unroll
    for (int mi = 0; mi < 8; ++mi) {
      acc[mi][0] = MFMA(a[mi], b0, acc[mi][0]);
      acc[mi][1] = MFMA(a[mi], b1, acc[mi][1]);
    }
    __builtin_amdgcn_s_setprio(0);
    __builtin_amdgcn_s_barrier();

    // ---------- phase 4: stage Akk1(t+2)->buf p (freed by ph3); read B2/3-kk1 --
    if (t < NT - 2) STAGE_A(p, 1, kA2);
    b2 = *(const bf16x8*)(rb + 32768 + (wc * 4 + 2) * 2048 + 1024 + laneoff);
    b3 = *(const bf16x8*)(rb + 32768 + (wc * 4 + 3) * 2048 + 1024 + laneoff);
    __builtin_amdgcn_s_barrier();
    asm volatile("s_waitcnt lgkmcnt(0)" ::: "memory");
    __builtin_amdgcn_sched_barrier(0);
    __builtin_amdgcn_s_setprio(1);
#pragma unroll
    for (int mi = 0; mi < 8; ++mi) {
      acc[mi][2] = MFMA(a[mi], b2, acc[mi][2]);
      acc[mi][3] = MFMA(a[mi], b3, acc[mi][3]);
    }
    __builtin_amdgcn_s_setprio(0);
    // gate 2: Akk0(t+1), Bkk0(t+1) must land (5 units issued after them)
    if (t < NT - 2)       { asm volatile("s_waitcnt vmcnt(10)" ::: "memory"); }
    else if (t == NT - 2) { asm volatile("s_waitcnt vmcnt(4)"  ::: "memory"); }
    else                  { asm volatile("s_waitcnt vmcnt(0)"  ::: "memory"); }
    __builtin_amdgcn_s_barrier();
  }

  // ---- epilogue: acc -> bf16 C ----
  const int rq = (l >> 4) * 4;
#pragma unroll
  for (int mi = 0; mi < 8; ++mi)
#pragma unroll
    for (int ni = 0; ni < 4; ++ni) {
      int row = m0 + wr * 128 + mi * 16 + rq;
      int col = n0 + wc * 64 + ni * 16 + lr;
      unsigned short* cp = Cq + (size_t)row * N3 + col;
#pragma unroll
      for (int r = 0; r < 4; ++r)
        cp[(size_t)r * N3] = f2bf(acc[mi][ni][r]);
    }
#undef STAGE_A
#undef STAGE_B
#undef MFMA
}

// ---- per (seq, head): LN(q), LN(k), softmax(q*s @ k^T) @ v; bf16 in ----
// mode 0: write bf16 [hi|lo] rows permrow(m) into a2 (feeds pass-1 GEMM)
// mode 1: write fp32 rows permrow(m) into out (final result)
__global__ __launch_bounds__(256) void attn(const unsigned short* __restrict__ qkv,
                                            const float* __restrict__ gamma,
                                            const float* __restrict__ beta,
                                            float* __restrict__ out,
                                            unsigned short* __restrict__ a2,
                                            int mode) {
  __shared__ float q[32][65], k[32][65], v[32][65];
  __shared__ float pr[32][33];
  __shared__ float mu[64], rs[64], gm[64], bt[64];
  const int tid = threadIdx.x;
  const int s = blockIdx.x >> 4, hd = blockIdx.x & 15;
  const size_t base = (size_t)s * 32 * 3072 + hd * 64;
  if (tid < 64) { gm[tid] = gamma[tid]; bt[tid] = beta[tid]; }
  {
    const int p = tid >> 3, d0 = (tid & 7) * 8;
    size_t r = base + (size_t)p * 3072 + d0;
    u16x8 qa = *(const u16x8*)(qkv + r);
    u16x8 ka = *(const u16x8*)(qkv + r + 1024);
    u16x8 va = *(const u16x8*)(qkv + r + 2048);
#pragma unroll
    for (int j = 0; j < 8; ++j) {
      q[p][d0 + j] = bf2f(qa[j]);
      k[p][d0 + j] = bf2f(ka[j]);
      v[p][d0 + j] = bf2f(va[j]);
    }
  }
  __syncthreads();
  {  // LN stats: 64 rows (q 0-31, k 32-63) x 4 threads each
    const int r = tid >> 2, qt = tid & 3;
    const float* row = (r < 32) ? q[r] : k[r - 32];
    float s1 = 0.f, s2 = 0.f;
#pragma unroll
    for (int d = qt * 16; d < qt * 16 + 16; ++d) { float x = row[d]; s1 += x; s2 += x * x; }
    s1 += __shfl_xor(s1, 1); s2 += __shfl_xor(s2, 1);
    s1 += __shfl_xor(s1, 2); s2 += __shfl_xor(s2, 2);
    if (qt == 0) {
      float m = s1 * 0.015625f;
      mu[r] = m;
      rs[r] = rsqrtf(s2 * 0.015625f - m * m + 1e-5f);
    }
  }
  __syncthreads();
  {
    const int p = tid >> 3, d0 = (tid & 7) * 8;
#pragma unroll
    for (int j = 0; j < 8; ++j) {
      int d = d0 + j;
      q[p][d] = ((q[p][d] - mu[p]) * rs[p] * gm[d] + bt[d]) * SCALE;
      k[p][d] = (k[p][d] - mu[32 + p]) * rs[32 + p] * gm[d] + bt[d];
    }
  }
  __syncthreads();
  {  // logits: 4 per thread
    const int r = tid >> 3, c0 = (tid & 7) * 4;
#pragma unroll
    for (int cc = 0; cc < 4; ++cc) {
      float a = 0.f;
      const float* qr = q[r]; const float* kr = k[c0 + cc];
#pragma unroll
      for (int d = 0; d < 64; ++d) a += qr[d] * kr[d];
      pr[r][c0 + cc] = a;
    }
  }
  __syncthreads();
  {  // softmax: 8 threads per row
    const int r = tid >> 3, c0 = (tid & 7) * 4;
    float e0 = pr[r][c0], e1 = pr[r][c0 + 1], e2 = pr[r][c0 + 2], e3 = pr[r][c0 + 3];
    float mx = fmaxf(fmaxf(e0, e1), fmaxf(e2, e3));
    mx = fmaxf(mx, __shfl_xor(mx, 1));
    mx = fmaxf(mx, __shfl_xor(mx, 2));
    mx = fmaxf(mx, __shfl_xor(mx, 4));
    e0 = __expf(e0 - mx); e1 = __expf(e1 - mx);
    e2 = __expf(e2 - mx); e3 = __expf(e3 - mx);
    float sum = e0 + e1 + e2 + e3;
    sum += __shfl_xor(sum, 1);
    sum += __shfl_xor(sum, 2);
    sum += __shfl_xor(sum, 4);
    float inv = 1.f / sum;
    pr[r][c0] = e0 * inv; pr[r][c0 + 1] = e1 * inv;
    pr[r][c0 + 2] = e2 * inv; pr[r][c0 + 3] = e3 * inv;
  }
  __syncthreads();
  {  // PV + permuted store
    const int p = tid >> 3, d0 = (tid & 7) * 8;
    float o[8] = {};
#pragma unroll
    for (int j = 0; j < 32; ++j) {
      float pj = pr[p][j];
#pragma unroll
      for (int d = 0; d < 8; ++d) o[d] += pj * v[j][d0 + d];
    }
    int pm = permrow(s * 32 + p);
    if (mode == 0) {
      u16x8 hi, lo;
#pragma unroll
      for (int d = 0; d < 8; ++d) {
        unsigned short h = f2bf(o[d]);
        hi[d] = h;
        lo[d] = f2bf(o[d] - bf2f(h));
      }
      unsigned short* dp = a2 + (size_t)pm * 2048 + hd * 64 + d0;
      *(u16x8*)dp          = hi;
      *(u16x8*)(dp + 1024) = lo;
    } else {
      float* op = out + (size_t)pm * 1024 + hd * 64 + d0;
#pragma unroll
      for (int d = 0; d < 8; ++d) op[d] = o[d];
    }
  }
}

extern "C" void kernel_launch(void* const* d_in, const int* in_sizes, int n_in,
                              void* d_out, int out_size, void* d_ws, size_t ws_size,
                              hipStream_t stream) {
  const float* x    = (const float*)d_in[0];
  const float* Wrow = (const float*)d_in[1];
  const float* Wcol = (const float*)d_in[2];
  const float* grow = (const float*)d_in[3];
  const float* brow = (const float*)d_in[4];
  const float* gcol = (const float*)d_in[5];
  const float* bcol = (const float*)d_in[6];
  float* out = (float*)d_out;

  char* ws = (char*)d_ws;
  const size_t szA2 = (size_t)MROWS * 2048 * 2;   // 67108864
  const size_t szB2 = (size_t)N3 * N3 * 2;        // 18874368
  unsigned short* A2   = (unsigned short*)ws;
  unsigned short* B2   = (unsigned short*)(ws + szA2);
  unsigned short* qkvb = (unsigned short*)(ws + szA2 + szB2);  // 16384*3072*2

  // pass 0 (rows)
  split_x<<<8192, 256, 0, stream>>>(x, A2);
  split_w<<<1536, 256, 0, stream>>>(Wrow, B2);
  gemm256<<<768, 512, 0, stream>>>(A2, B2, qkvb);
  attn<<<8192, 256, 0, stream>>>(qkvb, grow, brow, out, A2, 0);  // writes A2 (permuted)
  // pass 1 (cols)
  split_w<<<1536, 256, 0, stream>>>(Wcol, B2);
  gemm256<<<768, 512, 0, stream>>>(A2, B2, qkvb);
  attn<<<8192, 256, 0, stream>>>(qkvb, gcol, bcol, out, A2, 1);  // writes out
}